// Round 1
// baseline (394.173 us; speedup 1.0000x reference)
//
#include <hip/hip_runtime.h>

// RubiksShift forward: out[n,c,i,j] = bilinear(x[n,c], i+sh[c], j+sw[c]),
// zero outside the feature map. Memory-bound; one thread per output float4.

#define NDIM 16
#define CDIM 256
#define HDIM 112
#define WDIM 112

__global__ __launch_bounds__(256) void rubiks_shift_fwd(
    const float* __restrict__ x,      // [N, C, H, W]
    const float* __restrict__ shift,  // [2, C]
    float* __restrict__ out)          // [N, C, H, W]
{
    constexpr int HW  = HDIM * WDIM;   // 12544
    constexpr int HW4 = HW / 4;        // 3136 float4s per plane
    constexpr int W4  = WDIM / 4;      // 28 float4s per row
    constexpr int TOTAL4 = NDIM * CDIM * HW4;  // 12,845,056

    const int stride = gridDim.x * blockDim.x;
    for (int idx4 = blockIdx.x * blockDim.x + threadIdx.x;
         idx4 < TOTAL4; idx4 += stride)
    {
        // Decompose: plane = (n*C + c), row i, float4-col j4
        const int plane = idx4 / HW4;             // magic-mul
        const int rem   = idx4 - plane * HW4;
        const int i     = rem / W4;               // magic-mul
        const int j     = (rem - i * W4) * 4;     // element col of first output
        const int c     = plane & (CDIM - 1);     // C = 256 (pow2)

        // Per-channel shifts (2 KB table -> L1 hit, wave-uniform broadcast)
        const float sh = shift[c];
        const float sw = shift[CDIM + c];
        const float flh = floorf(sh);
        const float flw = floorf(sw);
        const float frh = sh - flh;               // in [0,1)
        const float frw = sw - flw;

        const int i0 = i + (int)flh;              // top source row
        const int j0 = j + (int)flw;              // leftmost source col

        const float* pl = x + (size_t)plane * HW;

        const bool r0ok = (unsigned)i0       < (unsigned)HDIM;
        const bool r1ok = (unsigned)(i0 + 1) < (unsigned)HDIM;
        // Clamp row addresses so loads are always in-bounds; mask values after.
        const int i0c = min(max(i0, 0), HDIM - 1);
        const int i1c = min(max(i0 + 1, 0), HDIM - 1);
        const float* row0 = pl + i0c * WDIM;
        const float* row1 = pl + i1c * WDIM;

        float a[5], b[5];
        #pragma unroll
        for (int k = 0; k < 5; ++k) {
            const int col  = j0 + k;
            const bool cok = (unsigned)col < (unsigned)WDIM;
            const int colc = min(max(col, 0), WDIM - 1);
            const float va = row0[colc];
            const float vb = row1[colc];
            a[k] = (r0ok & cok) ? va : 0.0f;
            b[k] = (r1ok & cok) ? vb : 0.0f;
        }

        const float wh1 = frh, wh0 = 1.0f - frh;
        const float ww1 = frw, ww0 = 1.0f - frw;

        float4 o;
        o.x = wh0 * (ww0 * a[0] + ww1 * a[1]) + wh1 * (ww0 * b[0] + ww1 * b[1]);
        o.y = wh0 * (ww0 * a[1] + ww1 * a[2]) + wh1 * (ww0 * b[1] + ww1 * b[2]);
        o.z = wh0 * (ww0 * a[2] + ww1 * a[3]) + wh1 * (ww0 * b[2] + ww1 * b[3]);
        o.w = wh0 * (ww0 * a[3] + ww1 * a[4]) + wh1 * (ww0 * b[3] + ww1 * b[4]);

        *reinterpret_cast<float4*>(out + (size_t)idx4 * 4) = o;
    }
}

extern "C" void kernel_launch(void* const* d_in, const int* in_sizes, int n_in,
                              void* d_out, int out_size, void* d_ws, size_t ws_size,
                              hipStream_t stream) {
    const float* x     = (const float*)d_in[0];
    const float* shift = (const float*)d_in[1];
    float* out         = (float*)d_out;

    constexpr int TOTAL4 = NDIM * CDIM * HDIM * WDIM / 4;
    const int block = 256;
    int grid = (TOTAL4 + block - 1) / block;
    if (grid > 2048) grid = 2048;   // grid-stride the rest

    rubiks_shift_fwd<<<grid, block, 0, stream>>>(x, shift, out);
}

// Round 2
// 354.867 us; speedup vs baseline: 1.1108x; 1.1108x over previous
//
#include <hip/hip_runtime.h>

// RubiksShift forward: out[n,c,i,j] = bilinear(x[n,c], i+sh[c], j+sw[c]),
// zero outside the feature map. Memory-bound.
// One thread per output float4; 4 aligned float4 input loads (2 rows x 2),
// wave-uniform shift => wave-uniform extraction offset s = j0 & 3.

#define NDIM 16
#define CDIM 256
#define HDIM 112
#define WDIM 112

__global__ __launch_bounds__(256) void rubiks_shift_fwd(
    const float* __restrict__ x,      // [N, C, H, W]
    const float* __restrict__ shift,  // [2, C]
    float* __restrict__ out)          // [N, C, H, W]
{
    constexpr int HW  = HDIM * WDIM;   // 12544
    constexpr int HW4 = HW / 4;        // 3136 float4s per plane
    constexpr int W4  = WDIM / 4;      // 28 float4s per row

    const int idx4 = blockIdx.x * 256 + threadIdx.x;   // grid is exact

    const int plane = idx4 / HW4;             // magic-mul
    const int rem   = idx4 - plane * HW4;
    const int i     = rem / W4;               // magic-mul
    const int j     = (rem - i * W4) * 4;     // element col of first output
    const int c     = plane & (CDIM - 1);     // C = 256 (pow2)

    // Per-channel shifts (2 KB table -> L1 hit, wave-uniform broadcast)
    const float sh = shift[c];
    const float sw = shift[CDIM + c];
    const float flh = floorf(sh);
    const float flw = floorf(sw);
    const float frh = sh - flh;               // in [0,1)
    const float frw = sw - flw;

    const int i0 = i + (int)flh;              // top source row
    const int j0 = j + (int)flw;              // leftmost source col

    const float* pl = x + (size_t)plane * HW;

    const bool r0ok = (unsigned)i0       < (unsigned)HDIM;
    const bool r1ok = (unsigned)(i0 + 1) < (unsigned)HDIM;
    const int i0c = min(max(i0, 0), HDIM - 1);
    const int i1c = min(max(i0 + 1, 0), HDIM - 1);

    // Aligned 2x float4 window per row covering cols [base, base+8) ⊇ [j0, j0+4].
    // base independent of the switch below -> loads issue before the branch.
    const int s    = j0 & 3;                  // wave-uniform (channel-uniform shift)
    const int base = j0 & ~3;
    const int a0   = max(base, 0);            // clamped slots are always masked cols
    const int a1   = min(base + 4, WDIM - 4);

    const float* row0 = pl + i0c * WDIM;
    const float* row1 = pl + i1c * WDIM;
    const float4 r0lo = *reinterpret_cast<const float4*>(row0 + a0);
    const float4 r0hi = *reinterpret_cast<const float4*>(row0 + a1);
    const float4 r1lo = *reinterpret_cast<const float4*>(row1 + a0);
    const float4 r1hi = *reinterpret_cast<const float4*>(row1 + a1);

    float a[5], b[5];
    switch (s) {   // wave-uniform branch, static extraction in each arm
    case 0:
        a[0]=r0lo.x; a[1]=r0lo.y; a[2]=r0lo.z; a[3]=r0lo.w; a[4]=r0hi.x;
        b[0]=r1lo.x; b[1]=r1lo.y; b[2]=r1lo.z; b[3]=r1lo.w; b[4]=r1hi.x;
        break;
    case 1:
        a[0]=r0lo.y; a[1]=r0lo.z; a[2]=r0lo.w; a[3]=r0hi.x; a[4]=r0hi.y;
        b[0]=r1lo.y; b[1]=r1lo.z; b[2]=r1lo.w; b[3]=r1hi.x; b[4]=r1hi.y;
        break;
    case 2:
        a[0]=r0lo.z; a[1]=r0lo.w; a[2]=r0hi.x; a[3]=r0hi.y; a[4]=r0hi.z;
        b[0]=r1lo.z; b[1]=r1lo.w; b[2]=r1hi.x; b[3]=r1hi.y; b[4]=r1hi.z;
        break;
    default:
        a[0]=r0lo.w; a[1]=r0hi.x; a[2]=r0hi.y; a[3]=r0hi.z; a[4]=r0hi.w;
        b[0]=r1lo.w; b[1]=r1hi.x; b[2]=r1hi.y; b[3]=r1hi.z; b[4]=r1hi.w;
        break;
    }

    #pragma unroll
    for (int k = 0; k < 5; ++k) {
        const bool cok = (unsigned)(j0 + k) < (unsigned)WDIM;
        a[k] = (r0ok && cok) ? a[k] : 0.0f;
        b[k] = (r1ok && cok) ? b[k] : 0.0f;
    }

    const float wh1 = frh, wh0 = 1.0f - frh;
    const float ww1 = frw, ww0 = 1.0f - frw;

    float4 o;
    o.x = wh0 * (ww0 * a[0] + ww1 * a[1]) + wh1 * (ww0 * b[0] + ww1 * b[1]);
    o.y = wh0 * (ww0 * a[1] + ww1 * a[2]) + wh1 * (ww0 * b[1] + ww1 * b[2]);
    o.z = wh0 * (ww0 * a[2] + ww1 * a[3]) + wh1 * (ww0 * b[2] + ww1 * b[3]);
    o.w = wh0 * (ww0 * a[3] + ww1 * a[4]) + wh1 * (ww0 * b[3] + ww1 * b[4]);

    *reinterpret_cast<float4*>(out + (size_t)idx4 * 4) = o;
}

extern "C" void kernel_launch(void* const* d_in, const int* in_sizes, int n_in,
                              void* d_out, int out_size, void* d_ws, size_t ws_size,
                              hipStream_t stream) {
    const float* x     = (const float*)d_in[0];
    const float* shift = (const float*)d_in[1];
    float* out         = (float*)d_out;

    constexpr int TOTAL4 = NDIM * CDIM * HDIM * WDIM / 4;  // 12,845,056
    constexpr int block  = 256;
    constexpr int grid   = TOTAL4 / block;                 // 50,176 (exact)

    rubiks_shift_fwd<<<grid, block, 0, stream>>>(x, shift, out);
}

// Round 4
// 351.127 us; speedup vs baseline: 1.1226x; 1.0106x over previous
//
#include <hip/hip_runtime.h>

// RubiksShift forward: out[n,c,i,j] = bilinear(x[n,c], i+sh[c], j+sw[c]),
// zero outside the map. |shift| < 1 so floor(shift) ∈ {-1, 0}.
// Tile: 2 output rows x 8 output cols per thread (16 outputs, 4 float4 stores).
// Input window: 3 rows x 12 cols = 9 aligned float4 loads. Wave-uniform
// (per-channel) extraction offset s = j0 & 3 -> switch with static extraction.

#define NDIM 16
#define CDIM 256
#define HDIM 112
#define WDIM 112

using f32x4 = __attribute__((ext_vector_type(4))) float;

__device__ __forceinline__ f32x4 ld4(const float* p) {
    return *reinterpret_cast<const f32x4*>(p);
}

template <int S>
__device__ __forceinline__ void extract9(f32x4 A, f32x4 B, f32x4 C, float t[9]) {
    float w[12];
    #pragma unroll
    for (int k = 0; k < 4; ++k) { w[k] = A[k]; w[4 + k] = B[k]; w[8 + k] = C[k]; }
    #pragma unroll
    for (int k = 0; k < 9; ++k) t[k] = w[S + k];   // compile-time indices only
}

__global__ __launch_bounds__(256) void rubiks_shift_fwd(
    const float* __restrict__ x,      // [N, C, H, W]
    const float* __restrict__ shift,  // [2, C]
    float* __restrict__ out)          // [N, C, H, W]
{
    constexpr int HW   = HDIM * WDIM;  // 12544
    constexpr int SEGW = WDIM / 8;     // 14 col segments
    constexpr int SEGH = HDIM / 2;     // 56 row pairs
    constexpr int PER_PLANE = SEGW * SEGH;  // 784 threads per plane

    const int idx   = blockIdx.x * 256 + threadIdx.x;   // grid exact
    const int plane = idx / PER_PLANE;                  // magic-mul
    const int rem   = idx - plane * PER_PLANE;
    const int ip    = rem / SEGW;                       // magic-mul
    const int jseg  = rem - ip * SEGW;
    const int i     = ip * 2;                           // first output row
    const int j     = jseg * 8;                         // first output col
    const int c     = plane & (CDIM - 1);

    const float sh  = shift[c];
    const float sw  = shift[CDIM + c];
    const float flh = floorf(sh);
    const float flw = floorf(sw);
    const float frh = sh - flh;                         // [0,1)
    const float frw = sw - flw;

    const int i0 = i + (int)flh;       // top source row, in [-1, 110]
    const int j0 = j + (int)flw;       // leftmost source col, in [-1, 104]

    const float* pl = x + (size_t)plane * HW;

    // Source rows i0, i0+1, i0+2. Middle row is always in [0,111].
    const int  i0c  = max(i0, 0);
    const int  i1   = i0 + 1;
    const int  i2c  = min(i0 + 2, HDIM - 1);
    const bool r0ok = i0 >= 0;
    const bool r2ok = (i0 + 2) < HDIM;

    // Aligned 3-float4 window [base, base+12) ⊇ taps [j0, j0+8].
    // Clamped q0/q2 only ever feed taps that the col mask zeroes.
    const int s  = j0 & 3;
    const int base = j0 & ~3;
    const int q0 = max(base, 0);
    const int q1 = base + 4;                 // always in [0, 108]
    const int q2 = min(base + 8, WDIM - 4);

    const float* r0 = pl + i0c * WDIM;
    const float* r1 = pl + i1  * WDIM;
    const float* r2 = pl + i2c * WDIM;

    const f32x4 A0 = ld4(r0 + q0), B0 = ld4(r0 + q1), C0 = ld4(r0 + q2);
    const f32x4 A1 = ld4(r1 + q0), B1 = ld4(r1 + q1), C1 = ld4(r1 + q2);
    const f32x4 A2 = ld4(r2 + q0), B2 = ld4(r2 + q1), C2 = ld4(r2 + q2);

    float t0[9], t1[9], t2[9];
    switch (s) {   // channel-uniform -> ≤2 arms per wave; arms are pure moves
    case 0:  extract9<0>(A0,B0,C0,t0); extract9<0>(A1,B1,C1,t1); extract9<0>(A2,B2,C2,t2); break;
    case 1:  extract9<1>(A0,B0,C0,t0); extract9<1>(A1,B1,C1,t1); extract9<1>(A2,B2,C2,t2); break;
    case 2:  extract9<2>(A0,B0,C0,t0); extract9<2>(A1,B1,C1,t1); extract9<2>(A2,B2,C2,t2); break;
    default: extract9<3>(A0,B0,C0,t0); extract9<3>(A1,B1,C1,t1); extract9<3>(A2,B2,C2,t2); break;
    }

    // Column zero-padding masks (shared across the 3 rows).
    #pragma unroll
    for (int k = 0; k < 9; ++k) {
        const bool cok = (unsigned)(j0 + k) < (unsigned)WDIM;
        t0[k] = cok ? t0[k] : 0.0f;
        t1[k] = cok ? t1[k] : 0.0f;
        t2[k] = cok ? t2[k] : 0.0f;
    }

    // Horizontal lerps; middle row's h1 is shared by both output rows.
    const float ww1 = frw, ww0 = 1.0f - frw;
    float h0[8], h1[8], h2[8];
    #pragma unroll
    for (int m = 0; m < 8; ++m) {
        h0[m] = ww0 * t0[m] + ww1 * t0[m + 1];
        h1[m] = ww0 * t1[m] + ww1 * t1[m + 1];
        h2[m] = ww0 * t2[m] + ww1 * t2[m + 1];
    }

    // Vertical lerps; row validity folded into the weights.
    const float wh1 = frh, wh0 = 1.0f - frh;
    const float w00 = r0ok ? wh0 : 0.0f;   // out row i   : w00*row(i0)   + wh1*row(i0+1)
    const float w11 = r2ok ? wh1 : 0.0f;   // out row i+1 : wh0*row(i0+1) + w11*row(i0+2)

    f32x4 o00, o01, o10, o11;
    #pragma unroll
    for (int m = 0; m < 4; ++m) {
        o00[m] = w00 * h0[m]     + wh1 * h1[m];
        o01[m] = w00 * h0[m + 4] + wh1 * h1[m + 4];
        o10[m] = wh0 * h1[m]     + w11 * h2[m];
        o11[m] = wh0 * h1[m + 4] + w11 * h2[m + 4];
    }

    float* po = out + (size_t)plane * HW + i * WDIM + j;
    __builtin_nontemporal_store(o00, reinterpret_cast<f32x4*>(po));
    __builtin_nontemporal_store(o01, reinterpret_cast<f32x4*>(po + 4));
    __builtin_nontemporal_store(o10, reinterpret_cast<f32x4*>(po + WDIM));
    __builtin_nontemporal_store(o11, reinterpret_cast<f32x4*>(po + WDIM + 4));
}

extern "C" void kernel_launch(void* const* d_in, const int* in_sizes, int n_in,
                              void* d_out, int out_size, void* d_ws, size_t ws_size,
                              hipStream_t stream) {
    const float* x     = (const float*)d_in[0];
    const float* shift = (const float*)d_in[1];
    float* out         = (float*)d_out;

    constexpr int THREADS = NDIM * CDIM * (HDIM / 2) * (WDIM / 8);  // 3,211,264
    constexpr int block   = 256;
    constexpr int grid    = THREADS / block;                        // 12,544 exact

    rubiks_shift_fwd<<<grid, block, 0, stream>>>(x, shift, out);
}

// Round 5
// 345.289 us; speedup vs baseline: 1.1416x; 1.0169x over previous
//
#include <hip/hip_runtime.h>

// RubiksShift forward: out[n,c,i,j] = bilinear(x[n,c], i+sh[c], j+sw[c]),
// zero outside the map. |shift| < 1 so floor(shift) ∈ {-1, 0}.
//
// Latency-bound fix (r4): all global traffic is streaming/contiguous.
// One workgroup per HALF-plane: stage 57 source rows (25.5 KB) into LDS with
// contiguous float4 loads (reg-staged, 7 loads in flight), then gather from
// LDS. Per-channel shift => extraction case (iflw ∈ {-1,0}) and weights are
// WORKGROUP-uniform. 4 conflict-free ds_read_b128 per output float4.

#define NDIM 16
#define CDIM 256
#define HDIM 112
#define WDIM 112

using f32x4 = __attribute__((ext_vector_type(4))) float;

__global__ __launch_bounds__(256) void rubiks_shift_fwd(
    const float* __restrict__ x,      // [N, C, H, W]
    const float* __restrict__ shift,  // [2, C]
    float* __restrict__ out)          // [N, C, H, W]
{
    constexpr int HW     = HDIM * WDIM;   // 12544
    constexpr int W4     = WDIM / 4;      // 28 float4 per row
    constexpr int SROWS  = 57;            // staged source rows per half
    constexpr int NSTG4  = SROWS * W4;    // 1596 float4 staged
    constexpr int NOUT4  = 56 * W4;       // 1568 float4 out per half

    __shared__ f32x4 lds4[NSTG4];         // 25,536 B

    const int bid   = blockIdx.x;
    const int tid   = threadIdx.x;
    const int plane = bid >> 1;           // (n*C + c)
    const int half  = bid & 1;            // 0: rows 0..55, 1: rows 56..111
    const int c     = plane & (CDIM - 1);

    // ---- stage: source rows sr0 .. sr0+56 (contiguous stream) ----
    const int sr0 = half ? (HDIM / 2 - 1) : 0;   // 55 or 0
    const f32x4* __restrict__ src =
        reinterpret_cast<const f32x4*>(x + (size_t)plane * HW + sr0 * WDIM);

    f32x4 r[6];
    #pragma unroll
    for (int t = 0; t < 6; ++t) r[t] = src[tid + t * 256];   // 6 KB/lane-group
    f32x4 rt;
    const bool tail = tid < (NSTG4 - 6 * 256);               // 60
    if (tail) rt = src[tid + 6 * 256];
    #pragma unroll
    for (int t = 0; t < 6; ++t) lds4[tid + t * 256] = r[t];
    if (tail) lds4[tid + 6 * 256] = rt;

    // ---- uniform per-channel decode ----
    const float sh  = shift[c];
    const float sw  = shift[CDIM + c];
    const float flh = floorf(sh);
    const float flw = floorf(sw);
    const float frh = sh - flh;           // [0,1)
    const float frw = sw - flw;
    const int  iflh = (int)flh;           // -1 or 0
    const bool neg  = flw < 0.0f;         // iflw == -1
    const float ww1 = frw, ww0 = 1.0f - frw;
    const float wh1 = frh, wh0 = 1.0f - frh;

    __syncthreads();

    const int row_base = half * 56;
    f32x4* __restrict__ dst =
        reinterpret_cast<f32x4*>(out + (size_t)plane * HW) + half * NOUT4;

    // ---- compute: 6 full iterations + tail of 32 ----
    #pragma unroll
    for (int t = 0; t < 7; ++t) {
        const int m = tid + t * 256;
        if (t == 6 && m >= NOUT4) break;

        const int i_loc = m / W4;                 // magic-mul
        const int j4    = m - i_loc * W4;

        const int i0  = row_base + i_loc + iflh;  // top source row (global)
        const int li0 = i0 - sr0;
        const int li0c = max(li0, 0);
        const int li1c = min(li0 + 1, SROWS - 1);
        const float w0 = (i0 >= 0)        ? wh0 : 0.0f;
        const float w1 = (i0 + 1 < HDIM)  ? wh1 : 0.0f;

        // aligned col window: lo covers taps base..base+3, hi the next 4
        const int jlo  = neg ? j4 - 1 : j4;
        const int jloc = max(jlo, 0);
        const int jhic = min(jlo + 1, W4 - 1);

        const f32x4 aL = lds4[li0c * W4 + jloc];
        const f32x4 aH = lds4[li0c * W4 + jhic];
        const f32x4 bL = lds4[li1c * W4 + jloc];
        const f32x4 bH = lds4[li1c * W4 + jhic];

        float ta[5], tb[5];
        if (neg) {  // taps j-1..j+3 : {lo.w, hi.x, hi.y, hi.z, hi.w}
            ta[0]=aL[3]; ta[1]=aH[0]; ta[2]=aH[1]; ta[3]=aH[2]; ta[4]=aH[3];
            tb[0]=bL[3]; tb[1]=bH[0]; tb[2]=bH[1]; tb[3]=bH[2]; tb[4]=bH[3];
            if (j4 == 0) { ta[0] = 0.0f; tb[0] = 0.0f; }      // col -1
        } else {    // taps j..j+4 : {lo.x, lo.y, lo.z, lo.w, hi.x}
            ta[0]=aL[0]; ta[1]=aL[1]; ta[2]=aL[2]; ta[3]=aL[3]; ta[4]=aH[0];
            tb[0]=bL[0]; tb[1]=bL[1]; tb[2]=bL[2]; tb[3]=bL[3]; tb[4]=bH[0];
            if (j4 == W4 - 1) { ta[4] = 0.0f; tb[4] = 0.0f; } // col 112
        }

        f32x4 o;
        #pragma unroll
        for (int k = 0; k < 4; ++k) {
            const float ha = ww0 * ta[k] + ww1 * ta[k + 1];
            const float hb = ww0 * tb[k] + ww1 * tb[k + 1];
            o[k] = w0 * ha + w1 * hb;
        }
        __builtin_nontemporal_store(o, dst + m);
    }
}

extern "C" void kernel_launch(void* const* d_in, const int* in_sizes, int n_in,
                              void* d_out, int out_size, void* d_ws, size_t ws_size,
                              hipStream_t stream) {
    const float* x     = (const float*)d_in[0];
    const float* shift = (const float*)d_in[1];
    float* out         = (float*)d_out;

    constexpr int grid = NDIM * CDIM * 2;   // 8192 workgroups (2 per plane)
    rubiks_shift_fwd<<<grid, 256, 0, stream>>>(x, shift, out);
}